// Round 13
// baseline (491.921 us; speedup 1.0000x reference)
//
#include <hip/hip_runtime.h>

// ---------------- problem constants ----------------
constexpr int Nn   = 100000;
constexpr int Ne   = 1600000;
constexpr int FINN = 64;
constexpr int Dh   = 20;
constexpr int Dout = 16;
constexpr float EPSV = 1e-5f;

// CSR build: two-pass radix by dst range (R5/R8 proven structure).
constexpr int NR  = 16;               // dst ranges (buckets)
constexpr int RSZ = Nn / NR;          // 6250 nodes per range (fits 13 bits)
constexpr int NSL = 32;               // slices per range for pass-2 parallelism
constexpr int P1B = 400;              // partition blocks
constexpr int P1E = Ne / P1B;         // 4000 edges per partition block

// ---------------- workspace layout (float units) ----------------
constexpr size_t OFF_WC1  = 0;         // 64*40 combined [A|B] layer1
constexpr size_t OFF_C1   = 2560;      // 32
constexpr size_t OFF_WCM  = 2592;      // 3 * 800
constexpr size_t OFF_CM   = 4992;      // 3 * 32
constexpr size_t OFF_WC5  = 5088;      // 20*32
constexpr size_t OFF_C5   = 5728;      // 32
constexpr size_t OFF_ST   = 5760;      // 4 layers * 64 (sum@+0, sumsq@+32)
constexpr size_t OFF_OFFS = 8192;      // u32, N+1 (padded 100352)
constexpr size_t OFF_BSUM = 208896;    // u32, 512
constexpr size_t OFF_CNT  = 209408;    // u32, N (padded 100352)
constexpr size_t OFF_CSR  = 309760;    // u32, Ne -> ends 1,909,760
constexpr size_t OFF_XA   = 1910784;   // u16 Nn*24 (1.2M fl); ebuf (u32 Ne = 1.6M fl) aliases -> reserve 1.6M
constexpr size_t OFF_XB   = 3510784;   // u16 Nn*24 (1.2M fl); part (u16 NR*NSL*RSZ = 1.6M fl) aliases -> reserve 1.6M
constexpr size_t OFF_HP   = 5110784;   // u16 Nn*24 (1.2M fl); bhT/obhT/rbase alias head (CSR-build phase only)
constexpr size_t OFF_BHT  = OFF_HP;            // u32, NR*P1B = 6400
constexpr size_t OFF_OBHT = OFF_HP + 6400;     // u32, NR*P1B = 6400
constexpr size_t OFF_RB   = OFF_HP + 12800;    // u32, NR+1
// total ~6.31M floats ≈ 25.2 MiB

// bf16 <-> f32 (bit-exact expand; RNE pack).
__device__ inline unsigned short f2b(float x) {
    unsigned b = __float_as_uint(x);
    return (unsigned short)((b + 0x7FFFu + ((b >> 16) & 1u)) >> 16);
}
__device__ inline float b2f(unsigned short u) {
    return __uint_as_float(((unsigned)u) << 16);
}
__device__ inline float blo(unsigned u) { return __uint_as_float(u << 16); }
__device__ inline float bhi(unsigned u) { return __uint_as_float(u & 0xFFFF0000u); }
__device__ inline unsigned bpack(float lo, float hi) {
    return (unsigned)f2b(lo) | ((unsigned)f2b(hi) << 16);
}

// ---------------- weight folding ----------------
// A = Wl@Wn, B = (Wr+Ws)@Wn, c = (bl+bs)@Wn + bn   (per layer)
__global__ void prep_weights(
    const float* __restrict__ Wl1, const float* __restrict__ bl1,
    const float* __restrict__ Wr1, const float* __restrict__ Ws1,
    const float* __restrict__ bs1, const float* __restrict__ Wn1,
    const float* __restrict__ bn1,
    const float* __restrict__ Wlm, const float* __restrict__ blm,
    const float* __restrict__ Wrm, const float* __restrict__ Wsm,
    const float* __restrict__ bsm, const float* __restrict__ Wnm,
    const float* __restrict__ bnm,
    const float* __restrict__ Wl5, const float* __restrict__ bl5,
    const float* __restrict__ Wr5, const float* __restrict__ Ws5,
    const float* __restrict__ bs5, const float* __restrict__ Wn5,
    const float* __restrict__ bn5,
    float* __restrict__ wc1, float* __restrict__ c1,
    float* __restrict__ wcm, float* __restrict__ cm,
    float* __restrict__ wc5, float* __restrict__ c5)
{
    int layer = blockIdx.x;
    int t = threadIdx.x;
    if (layer == 0) {
        for (int idx = t; idx < FINN * Dh; idx += blockDim.x) {
            int k = idx / Dh, j = idx % Dh;
            float a = 0.f, b = 0.f;
            for (int d = 0; d < Dh; ++d) {
                float wn = Wn1[d * Dh + j];
                a += Wl1[k * Dh + d] * wn;
                b += (Wr1[k * Dh + d] + Ws1[k * Dh + d]) * wn;
            }
            wc1[k * 40 + j] = a;
            wc1[k * 40 + 20 + j] = b;
        }
        for (int j = t; j < Dh; j += blockDim.x) {
            float c0 = 0.f;
            for (int d = 0; d < Dh; ++d) c0 += (bl1[d] + bs1[d]) * Wn1[d * Dh + j];
            c1[j] = c0 + bn1[j];
        }
    } else if (layer <= 3) {
        int i = layer - 1;
        const float* Wl = Wlm + i * Dh * Dh;
        const float* Wr = Wrm + i * Dh * Dh;
        const float* Ws = Wsm + i * Dh * Dh;
        const float* Wn = Wnm + i * Dh * Dh;
        const float* bl = blm + i * Dh;
        const float* bs = bsm + i * Dh;
        const float* bn = bnm + i * Dh;
        float* wc = wcm + i * 800;
        float* cc = cm + i * 32;
        for (int idx = t; idx < Dh * Dh; idx += blockDim.x) {
            int k = idx / Dh, j = idx % Dh;
            float a = 0.f, b = 0.f;
            for (int d = 0; d < Dh; ++d) {
                float wn = Wn[d * Dh + j];
                a += Wl[k * Dh + d] * wn;
                b += (Wr[k * Dh + d] + Ws[k * Dh + d]) * wn;
            }
            wc[k * 40 + j] = a;
            wc[k * 40 + 20 + j] = b;
        }
        for (int j = t; j < Dh; j += blockDim.x) {
            float c0 = 0.f;
            for (int d = 0; d < Dh; ++d) c0 += (bl[d] + bs[d]) * Wn[d * Dh + j];
            cc[j] = c0 + bn[j];
        }
    } else {
        for (int idx = t; idx < Dh * Dout; idx += blockDim.x) {
            int k = idx / Dout, j = idx % Dout;
            float a = 0.f, b = 0.f;
            for (int d = 0; d < Dh; ++d) {
                float wn = Wn5[d * Dout + j];
                a += Wl5[k * Dh + d] * wn;
                b += (Wr5[k * Dh + d] + Ws5[k * Dh + d]) * wn;
            }
            wc5[k * 32 + j] = a;
            wc5[k * 32 + 16 + j] = b;
        }
        for (int j = t; j < Dout; j += blockDim.x) {
            float c0 = 0.f;
            for (int d = 0; d < Dh; ++d) c0 += (bl5[d] + bs5[d]) * Wn5[d * Dout + j];
            c5[j] = c0 + bn5[j];
        }
    }
}

// ---------------- CSR build: two-pass radix, no global atomics ----------------
__global__ __launch_bounds__(256) void hist1(const int* __restrict__ dst, unsigned* __restrict__ bhT) {
    __shared__ unsigned h[16 * NR];
    int b = blockIdx.x, t = threadIdx.x;
    for (int i = t; i < 16 * NR; i += 256) h[i] = 0;
    __syncthreads();
    int sub = t & 15;
    int e0 = b * P1E, e1 = min(e0 + P1E, Ne);
    for (int e = e0 + t; e < e1; e += 256) {
        int r = dst[e] / RSZ;
        atomicAdd(&h[sub * NR + r], 1u);
    }
    __syncthreads();
    if (t < NR) {
        unsigned s = 0;
        for (int i = 0; i < 16; ++i) s += h[i * NR + t];
        bhT[t * P1B + b] = s;   // transposed: [range][block]
    }
}

__global__ __launch_bounds__(1024) void scan1(
    const unsigned* __restrict__ bhT, unsigned* __restrict__ obhT, unsigned* __restrict__ rbase)
{
    __shared__ unsigned rtot[NR];
    int t = threadIdx.x;
    int w = t >> 6, lane = t & 63;
    constexpr int PER = (P1B + 63) / 64;  // 7
    if (w < NR) {
        unsigned v[PER];
        unsigned s = 0;
#pragma unroll
        for (int i = 0; i < PER; ++i) {
            int b = lane * PER + i;
            v[i] = (b < P1B) ? bhT[w * P1B + b] : 0u;
            s += v[i];
        }
        unsigned val = s;
        for (int off = 1; off < 64; off <<= 1) {
            unsigned u = __shfl_up(val, off, 64);
            if (lane >= off) val += u;
        }
        unsigned run = val - s;  // exclusive
#pragma unroll
        for (int i = 0; i < PER; ++i) {
            int b = lane * PER + i;
            if (b < P1B) obhT[w * P1B + b] = run;
            run += v[i];
        }
        if (lane == 63) rtot[w] = val;
    }
    __syncthreads();
    if (t == 0) {
        unsigned base = 0;
        for (int r = 0; r < NR; ++r) { rbase[r] = base; base += rtot[r]; }
        rbase[NR] = base;
    }
}

__global__ __launch_bounds__(256) void scatter1(
    const int* __restrict__ src, const int* __restrict__ dst,
    const unsigned* __restrict__ obhT, const unsigned* __restrict__ rbase,
    unsigned* __restrict__ ebuf)
{
    __shared__ unsigned cur[NR];
    int b = blockIdx.x, t = threadIdx.x;
    if (t < NR) cur[t] = rbase[t] + obhT[t * P1B + b];
    __syncthreads();
    int e0 = b * P1E, e1 = min(e0 + P1E, Ne);
    for (int e = e0 + t; e < e1; e += 256) {
        int d = dst[e];
        int r = d / RSZ;
        unsigned dl = (unsigned)(d - r * RSZ);
        unsigned pos = atomicAdd(&cur[r], 1u);
        ebuf[pos] = (dl << 17) | (unsigned)src[e];
    }
}

__global__ __launch_bounds__(256) void hist2(
    const unsigned* __restrict__ ebuf, const unsigned* __restrict__ rbase,
    unsigned short* __restrict__ part)
{
    __shared__ unsigned h[RSZ];   // 25 KB
    int b = blockIdx.x, t = threadIdx.x;
    int r = b % NR, s = b / NR;
    for (int i = t; i < RSZ; i += 256) h[i] = 0;
    __syncthreads();
    unsigned lo = rbase[r], hi = rbase[r + 1];
    unsigned step = (hi - lo + NSL - 1) / NSL;
    unsigned e0 = lo + (unsigned)s * step;
    unsigned e1 = e0 + step; if (e1 > hi) e1 = hi;
    for (unsigned e = e0 + t; e < e1; e += 256)
        atomicAdd(&h[ebuf[e] >> 17], 1u);
    __syncthreads();
    unsigned short* p = part + (size_t)b * RSZ;
    for (int i = t; i < RSZ; i += 256) p[i] = (unsigned short)h[i];
}

__global__ void col_prefix(unsigned short* __restrict__ part, unsigned* __restrict__ cnt) {
    int d = blockIdx.x * blockDim.x + threadIdx.x;
    if (d >= Nn) return;
    int r = d / RSZ, dl = d - r * RSZ;
    unsigned run = 0;
#pragma unroll
    for (int s = 0; s < NSL; ++s) {
        size_t idx = ((size_t)s * NR + r) * RSZ + dl;
        unsigned v = part[idx];
        part[idx] = (unsigned short)run;
        run += v;
    }
    cnt[d] = run;
}

__global__ void scan_blocksums(const unsigned* __restrict__ cnt, unsigned* __restrict__ bsum, int n) {
    __shared__ unsigned sd[256];
    int b = blockIdx.x, t = threadIdx.x;
    int base = b * 1024;
    unsigned s = 0;
    for (int i = t; i < 1024; i += 256) {
        int idx = base + i;
        if (idx < n) s += cnt[idx];
    }
    sd[t] = s;
    __syncthreads();
    for (int off = 128; off > 0; off >>= 1) {
        if (t < off) sd[t] += sd[t + off];
        __syncthreads();
    }
    if (t == 0) bsum[b] = sd[0];
}

__global__ void scan_bsum(unsigned* __restrict__ bsum, int nb) {
    __shared__ unsigned sh[128];
    int t = threadIdx.x;
    unsigned v = (t < nb) ? bsum[t] : 0u;
    sh[t] = v;
    __syncthreads();
    for (int off = 1; off < 128; off <<= 1) {
        unsigned add = (t >= off) ? sh[t - off] : 0u;
        __syncthreads();
        sh[t] += add;
        __syncthreads();
    }
    if (t < nb) bsum[t] = sh[t] - v;  // exclusive
}

__global__ void scan_final(const unsigned* __restrict__ cnt, const unsigned* __restrict__ bsum,
                           unsigned* __restrict__ offs, int n) {
    __shared__ unsigned wsum[4], woff[4];
    int b = blockIdx.x, t = threadIdx.x;
    int base = b * 1024 + t * 4;
    unsigned v[4];
    unsigned s = 0;
#pragma unroll
    for (int i = 0; i < 4; ++i) {
        int idx = base + i;
        v[i] = (idx < n) ? cnt[idx] : 0u;
        s += v[i];
    }
    unsigned lane = t & 63;
    int w = t >> 6;
    unsigned val = s;
    for (int off = 1; off < 64; off <<= 1) {
        unsigned u = __shfl_up(val, off, 64);
        if (lane >= off) val += u;
    }
    if (lane == 63) wsum[w] = val;
    __syncthreads();
    if (t == 0) {
        unsigned r = 0;
        for (int i = 0; i < 4; ++i) { woff[i] = r; r += wsum[i]; }
    }
    __syncthreads();
    unsigned run = bsum[b] + woff[w] + (val - s);
#pragma unroll
    for (int i = 0; i < 4; ++i) {
        int idx = base + i;
        if (idx < n) {
            offs[idx] = run;
            run += v[i];
            if (idx == n - 1) offs[n] = run;
        }
    }
}

__global__ __launch_bounds__(256) void fill2(
    const unsigned* __restrict__ ebuf, const unsigned* __restrict__ rbase,
    const unsigned* __restrict__ offs, const unsigned short* __restrict__ part,
    unsigned* __restrict__ csr)
{
    __shared__ unsigned cur[RSZ];   // 25 KB
    int b = blockIdx.x, t = threadIdx.x;
    int r = b % NR, s = b / NR;
    int lon = r * RSZ;
    const unsigned short* p = part + (size_t)b * RSZ;
    for (int i = t; i < RSZ; i += 256)
        cur[i] = offs[lon + i] + p[i];
    __syncthreads();
    unsigned lo = rbase[r], hi = rbase[r + 1];
    unsigned step = (hi - lo + NSL - 1) / NSL;
    unsigned e0 = lo + (unsigned)s * step;
    unsigned e1 = e0 + step; if (e1 > hi) e1 = hi;
    for (unsigned e = e0 + t; e < e1; e += 256) {
        unsigned v = ebuf[e];
        unsigned pos = atomicAdd(&cur[v >> 17], 1u);
        csr[pos] = v & 0x1FFFFu;
    }
}

// ---------------- fused (lazy-BN+ReLU) + projection, lane-split ----------------
// CL = 2*(XS/8) lanes per node; each lane computes 8 of the 2*FO outputs and
// writes one 16B chunk of xa or xb. Weights staged in LDS. Grid = Nn*CL threads.
template <int FINt, int FO, bool NORM, bool INBF16>
__global__ __launch_bounds__(256) void gemm_kernel(
    const void* __restrict__ xin_, const float* __restrict__ stats,
    const float* __restrict__ g, const float* __restrict__ be,
    const float* __restrict__ wc, const float* __restrict__ cvec,
    unsigned short* __restrict__ xa, unsigned short* __restrict__ xb)
{
    constexpr int XS  = ((FO + 7) / 8) * 8;    // output row stride (u16)
    constexpr int XSI = ((FINt + 7) / 8) * 8;  // input row stride when bf16
    constexpr int CH  = XS / 8;                // 16B chunks per half
    constexpr int CL  = 2 * CH;                // lanes per node
    __shared__ float swl[FINt * 2 * FO + 8];   // +8: OOB-j reads stay in-bounds
    __shared__ float sscale[Dh], sshift[Dh];
    int t = threadIdx.x;
    for (int i = t; i < FINt * 2 * FO; i += 256) swl[i] = wc[i];
    if (t < 8) swl[FINt * 2 * FO + t] = 0.f;
    if (NORM) {
        if (t < Dh) {
            float mu = stats[t] * (1.0f / Nn);
            float var = stats[32 + t] * (1.0f / Nn) - mu * mu;
            float sc = g[t] * rsqrtf(var + EPSV);
            sscale[t] = sc;
            sshift[t] = be[t] - mu * sc;
        }
    }
    __syncthreads();
    int tid = blockIdx.x * 256 + t;
    int n = tid / CL;
    int c = tid % CL;
    if (n >= Nn) return;
    int half = c / CH, cc = c % CH;
    int off = half * FO + cc * 8;
    int jmax = (cc == CH - 1) ? (FO - (CH - 1) * 8) : 8;

    float acc[8];
#pragma unroll
    for (int j = 0; j < 8; ++j) acc[j] = 0.f;

#pragma unroll
    for (int k4 = 0; k4 < FINt / 4; ++k4) {
        float xs[4];
        if (INBF16) {
            const unsigned short* xr = (const unsigned short*)xin_ + (size_t)n * XSI;
            ushort4 v = *(const ushort4*)(xr + 4 * k4);
            xs[0] = b2f(v.x); xs[1] = b2f(v.y); xs[2] = b2f(v.z); xs[3] = b2f(v.w);
        } else {
            const float* xr = (const float*)xin_ + (size_t)n * FINt;
            float4 v = *(const float4*)(xr + 4 * k4);
            xs[0] = v.x; xs[1] = v.y; xs[2] = v.z; xs[3] = v.w;
        }
        if (NORM) {
#pragma unroll
            for (int kk = 0; kk < 4; ++kk)
                xs[kk] = fmaxf(xs[kk] * sscale[4 * k4 + kk] + sshift[4 * k4 + kk], 0.0f);
        }
#pragma unroll
        for (int kk = 0; kk < 4; ++kk) {
            float xk = xs[kk];
            const float* wr = &swl[(4 * k4 + kk) * (2 * FO) + off];
#pragma unroll
            for (int j = 0; j < 8; ++j) acc[j] = fmaf(xk, wr[j], acc[j]);
        }
    }

    float hv[8];
#pragma unroll
    for (int j = 0; j < 8; ++j) hv[j] = acc[j];
    if (half) {
#pragma unroll
        for (int j = 0; j < 8; ++j) hv[j] += cvec[cc * 8 + j];   // cvec padded to 32
    }
#pragma unroll
    for (int j = 0; j < 8; ++j) if (j >= jmax) hv[j] = 0.f;

    unsigned short* dstp = (half ? xb : xa) + (size_t)n * XS + cc * 8;
    uint4 w;
    w.x = bpack(hv[0], hv[1]); w.y = bpack(hv[2], hv[3]);
    w.z = bpack(hv[4], hv[5]); w.w = bpack(hv[6], hv[7]);
    *(uint4*)dstp = w;
}

// ---------------- pull aggregation + combine (+ BN stats) ----------------
// 8 threads per node: (s ∈ {0,1} edge-half) × (c ∈ {0..3} chunk slot, c<C active).
// Each active thread gathers ONE 16B uint4 per edge over HALF the node's edges
// (masked 8-deep bursts), then halves combine via __shfl_xor(…, 4) in-register.
// Doubles outstanding-gather concurrency vs R12 (tests the concurrency model).
template <int F, bool WITH_STATS, bool OUTBF16>
__global__ __launch_bounds__(256) void pull_kernel(
    const unsigned* __restrict__ offs, const unsigned* __restrict__ csr,
    const unsigned short* __restrict__ xa, const unsigned short* __restrict__ xb,
    void* __restrict__ out_, float* __restrict__ stats)
{
    constexpr int C  = (F + 7) / 8;   // active chunks per node (3 for F=20, 2 for F=16)
    constexpr int XS = C * 8;
    constexpr int TPN = 8;            // threads per node (divides wave64)
    __shared__ float sstat[2 * F];
    int t = threadIdx.x;
    if (WITH_STATS) {
        if (t < 2 * F) sstat[t] = 0.f;
        __syncthreads();
    }
    int tid = blockIdx.x * 256 + t;
    int n = tid / TPN;
    int sub = tid % TPN;
    int s = sub >> 2;        // edge half
    int c = sub & 3;         // chunk slot
    bool cact = (c < C);
    bool act = (n < Nn);
    int valid = (c == C - 1) ? (F - 8 * (C - 1)) : 8;

    float acc[8];
#pragma unroll
    for (int j = 0; j < 8; ++j) acc[j] = 0.f;
    unsigned b = 0, e = 0;
    if (act) { b = offs[n]; e = offs[n + 1]; }
    if (act && cact && e > b) {
        unsigned len = e - b;
        unsigned hl = (len + 1) >> 1;
        unsigned k0 = b + (s ? hl : 0u);
        unsigned k1 = s ? e : (b + hl);
        const unsigned short* base = xa + c * 8;
        for (unsigned k = k0; k < k1; k += 8) {
            unsigned si[8];
            float m[8];
#pragma unroll
            for (int i = 0; i < 8; ++i) {
                unsigned kk = k + i;
                bool in = kk < k1;
                si[i] = csr[in ? kk : b];
                m[i] = in ? 1.0f : 0.0f;
            }
            uint4 v[8];
#pragma unroll
            for (int i = 0; i < 8; ++i) v[i] = *(const uint4*)(base + (size_t)si[i] * XS);
#pragma unroll
            for (int i = 0; i < 8; ++i) {
                acc[0] = fmaf(m[i], blo(v[i].x), acc[0]);
                acc[1] = fmaf(m[i], bhi(v[i].x), acc[1]);
                acc[2] = fmaf(m[i], blo(v[i].y), acc[2]);
                acc[3] = fmaf(m[i], bhi(v[i].y), acc[3]);
                acc[4] = fmaf(m[i], blo(v[i].z), acc[4]);
                acc[5] = fmaf(m[i], bhi(v[i].z), acc[5]);
                acc[6] = fmaf(m[i], blo(v[i].w), acc[6]);
                acc[7] = fmaf(m[i], bhi(v[i].w), acc[7]);
            }
        }
    }
    // combine the two edge-halves: partner lane is sub^4 within the same node group
#pragma unroll
    for (int j = 0; j < 8; ++j) acc[j] += __shfl_xor(acc[j], 4, 64);

    float h[8];
    if (act && cact && s == 0) {
        float inv = 1.0f / fmaxf((float)(e - b), 1.0f);
        uint4 xv = *(const uint4*)(xb + (size_t)n * XS + c * 8);
        float xf[8] = { blo(xv.x), bhi(xv.x), blo(xv.y), bhi(xv.y),
                        blo(xv.z), bhi(xv.z), blo(xv.w), bhi(xv.w) };
#pragma unroll
        for (int j = 0; j < 8; ++j) h[j] = fmaf(acc[j], inv, xf[j]);
        if (OUTBF16) {
            unsigned short* o = (unsigned short*)out_ + (size_t)n * XS + c * 8;
            if (valid == 8) {
                uint4 w;
                w.x = bpack(h[0], h[1]); w.y = bpack(h[2], h[3]);
                w.z = bpack(h[4], h[5]); w.w = bpack(h[6], h[7]);
                *(uint4*)o = w;
            } else {
                ushort4 w4;
                w4.x = f2b(h[0]); w4.y = f2b(h[1]); w4.z = f2b(h[2]); w4.w = f2b(h[3]);
                *(ushort4*)o = w4;
            }
        } else {
            float* o = (float*)out_ + (size_t)n * F + c * 8;   // final out unpadded
            float4 v0; v0.x = h[0]; v0.y = h[1]; v0.z = h[2]; v0.w = h[3];
            *(float4*)o = v0;
            if (valid == 8) {
                float4 v1; v1.x = h[4]; v1.y = h[5]; v1.z = h[6]; v1.w = h[7];
                *(float4*)(o + 4) = v1;
            }
        }
    }
    if (WITH_STATS) {
        if (act && cact && s == 0) {
            for (int j = 0; j < valid; ++j) {
                atomicAdd(&sstat[c * 8 + j], h[j]);
                atomicAdd(&sstat[F + c * 8 + j], h[j] * h[j]);
            }
        }
        __syncthreads();
        if (t < F) {
            atomicAdd(&stats[t], sstat[t]);
        } else if (t < 2 * F) {
            atomicAdd(&stats[32 + (t - F)], sstat[t]);
        }
    }
}

// ---------------- launch ----------------
extern "C" void kernel_launch(void* const* d_in, const int* in_sizes, int n_in,
                              void* d_out, int out_size, void* d_ws, size_t ws_size,
                              hipStream_t stream) {
    const float* x   = (const float*)d_in[0];
    const int* ei    = (const int*)d_in[1];
    const int* esrc  = ei;
    const int* edst  = ei + Ne;
    const float* Wl1 = (const float*)d_in[3];
    const float* bl1 = (const float*)d_in[4];
    const float* Wr1 = (const float*)d_in[5];
    const float* Ws1 = (const float*)d_in[6];
    const float* bs1 = (const float*)d_in[7];
    const float* Wn1 = (const float*)d_in[8];
    const float* bn1 = (const float*)d_in[9];
    const float* g1  = (const float*)d_in[10];
    const float* be1 = (const float*)d_in[11];
    const float* Wlm = (const float*)d_in[12];
    const float* blm = (const float*)d_in[13];
    const float* Wrm = (const float*)d_in[14];
    const float* Wsm = (const float*)d_in[15];
    const float* bsm = (const float*)d_in[16];
    const float* Wnm = (const float*)d_in[17];
    const float* bnm = (const float*)d_in[18];
    const float* gm  = (const float*)d_in[19];
    const float* bem = (const float*)d_in[20];
    const float* Wl5 = (const float*)d_in[21];
    const float* bl5 = (const float*)d_in[22];
    const float* Wr5 = (const float*)d_in[23];
    const float* Ws5 = (const float*)d_in[24];
    const float* bs5 = (const float*)d_in[25];
    const float* Wn5 = (const float*)d_in[26];
    const float* bn5 = (const float*)d_in[27];

    float* ws   = (float*)d_ws;
    unsigned* u = (unsigned*)d_ws;
    float* wc1   = ws + OFF_WC1;
    float* c1    = ws + OFF_C1;
    float* wcm   = ws + OFF_WCM;
    float* cm    = ws + OFF_CM;
    float* wc5   = ws + OFF_WC5;
    float* c5    = ws + OFF_C5;
    float* stats = ws + OFF_ST;
    unsigned* offs = u + OFF_OFFS;
    unsigned* bsum = u + OFF_BSUM;
    unsigned* cnt  = u + OFF_CNT;
    unsigned* csr  = u + OFF_CSR;
    unsigned short* xa = (unsigned short*)(ws + OFF_XA);
    unsigned* ebuf = u + OFF_XA;                           // aliases xa region (dead before gemm1)
    unsigned short* xb = (unsigned short*)(ws + OFF_XB);
    unsigned short* part = (unsigned short*)(ws + OFF_XB); // aliases xb region (dead before gemm1)
    unsigned short* hp = (unsigned short*)(ws + OFF_HP);
    unsigned* bhT  = u + OFF_BHT;                          // alias hp head (CSR-build phase only)
    unsigned* obhT = u + OFF_OBHT;
    unsigned* rbase = u + OFF_RB;

    hipMemsetAsync(stats, 0, 256 * sizeof(float), stream);

    prep_weights<<<5, 256, 0, stream>>>(Wl1, bl1, Wr1, Ws1, bs1, Wn1, bn1,
                                        Wlm, blm, Wrm, Wsm, bsm, Wnm, bnm,
                                        Wl5, bl5, Wr5, Ws5, bs5, Wn5, bn5,
                                        wc1, c1, wcm, cm, wc5, c5);

    // ---- CSR build (two-pass radix, no global atomics) ----
    hist1<<<P1B, 256, 0, stream>>>(edst, bhT);
    scan1<<<1, 1024, 0, stream>>>(bhT, obhT, rbase);
    scatter1<<<P1B, 256, 0, stream>>>(esrc, edst, obhT, rbase, ebuf);
    hist2<<<NR * NSL, 256, 0, stream>>>(ebuf, rbase, part);
    col_prefix<<<(Nn + 255) / 256, 256, 0, stream>>>(part, cnt);
    constexpr int NB = (Nn + 1023) / 1024;  // 98
    scan_blocksums<<<NB, 256, 0, stream>>>(cnt, bsum, Nn);
    scan_bsum<<<1, 128, 0, stream>>>(bsum, NB);
    scan_final<<<NB, 256, 0, stream>>>(cnt, bsum, offs, Nn);
    fill2<<<NR * NSL, 256, 0, stream>>>(ebuf, rbase, offs, part, csr);

    int gblk20 = (Nn * 6 + 255) / 256;        // 2344 (gemm FO=20: 6 lanes/node)
    int gblk16 = (Nn * 4 + 255) / 256;        // 1563 (gemm FO=16: 4 lanes/node)
    int pblk   = (Nn * 8 + 255) / 256;        // 3125 (pull: 8 threads/node)

    // layer 1
    gemm_kernel<FINN, Dh, false, false><<<gblk20, 256, 0, stream>>>(x, nullptr, nullptr, nullptr, wc1, c1, xa, xb);
    pull_kernel<Dh, true, true><<<pblk, 256, 0, stream>>>(offs, csr, xa, xb, hp, stats + 0);
    // layer 2
    gemm_kernel<Dh, Dh, true, true><<<gblk20, 256, 0, stream>>>(hp, stats + 0, g1, be1, wcm + 0, cm + 0, xa, xb);
    pull_kernel<Dh, true, true><<<pblk, 256, 0, stream>>>(offs, csr, xa, xb, hp, stats + 64);
    // layer 3
    gemm_kernel<Dh, Dh, true, true><<<gblk20, 256, 0, stream>>>(hp, stats + 64, gm + 0, bem + 0, wcm + 800, cm + 32, xa, xb);
    pull_kernel<Dh, true, true><<<pblk, 256, 0, stream>>>(offs, csr, xa, xb, hp, stats + 128);
    // layer 4
    gemm_kernel<Dh, Dh, true, true><<<gblk20, 256, 0, stream>>>(hp, stats + 128, gm + 20, bem + 20, wcm + 1600, cm + 64, xa, xb);
    pull_kernel<Dh, true, true><<<pblk, 256, 0, stream>>>(offs, csr, xa, xb, hp, stats + 192);
    // layer 5 (no BN/ReLU at output; lazy-norm of layer-4 applied in gemm)
    gemm_kernel<Dh, Dout, true, true><<<gblk16, 256, 0, stream>>>(hp, stats + 192, gm + 40, bem + 40, wc5, c5, xa, xb);
    pull_kernel<Dout, false, false><<<pblk, 256, 0, stream>>>(offs, csr, xa, xb, d_out, nullptr);
}

// Round 14
// 344.335 us; speedup vs baseline: 1.4286x; 1.4286x over previous
//
#include <hip/hip_runtime.h>

// ---------------- problem constants ----------------
constexpr int Nn   = 100000;
constexpr int Ne   = 1600000;
constexpr int FINN = 64;
constexpr int Dh   = 20;
constexpr int Dout = 16;
constexpr float EPSV = 1e-5f;

// CSR build: two-pass radix by dst range (R5/R8 proven structure).
constexpr int NR  = 16;               // dst ranges (buckets)
constexpr int RSZ = Nn / NR;          // 6250 nodes per range (fits 13 bits)
constexpr int NSL = 32;               // slices per range for pass-2 parallelism
constexpr int P1B = 400;              // partition blocks
constexpr int P1E = Ne / P1B;         // 4000 edges per partition block

// ---------------- workspace layout (float units) ----------------
constexpr size_t OFF_WC1  = 0;         // 64*40 combined [A|B] layer1
constexpr size_t OFF_C1   = 2560;      // 32
constexpr size_t OFF_WCM  = 2592;      // 3 * 800
constexpr size_t OFF_CM   = 4992;      // 3 * 32
constexpr size_t OFF_WC5  = 5088;      // 20*32
constexpr size_t OFF_C5   = 5728;      // 32
constexpr size_t OFF_ST   = 5760;      // 4 layers * 64 (sum@+0, sumsq@+32)
constexpr size_t OFF_OFFS = 8192;      // u32, N+1 (padded 100352)
constexpr size_t OFF_BSUM = 208896;    // u32, 512
constexpr size_t OFF_CNT  = 209408;    // u32, N (padded 100352)
constexpr size_t OFF_CSR  = 309760;    // u32, Ne -> ends 1,909,760
constexpr size_t OFF_XA   = 1910784;   // u16 Nn*24 (1.2M fl); ebuf (u32 Ne = 1.6M fl) aliases -> reserve 1.6M
constexpr size_t OFF_XB   = 3510784;   // u16 Nn*24 (1.2M fl); part (u16 NR*NSL*RSZ = 1.6M fl) aliases -> reserve 1.6M
constexpr size_t OFF_HP   = 5110784;   // u16 Nn*24 (1.2M fl); bhT/obhT/rbase alias head (CSR-build phase only)
constexpr size_t OFF_BHT  = OFF_HP;            // u32, NR*P1B = 6400
constexpr size_t OFF_OBHT = OFF_HP + 6400;     // u32, NR*P1B = 6400
constexpr size_t OFF_RB   = OFF_HP + 12800;    // u32, NR+1
// total ~6.31M floats ≈ 25.2 MiB

// bf16 <-> f32 (bit-exact expand; RNE pack).
__device__ inline unsigned short f2b(float x) {
    unsigned b = __float_as_uint(x);
    return (unsigned short)((b + 0x7FFFu + ((b >> 16) & 1u)) >> 16);
}
__device__ inline float b2f(unsigned short u) {
    return __uint_as_float(((unsigned)u) << 16);
}
__device__ inline float blo(unsigned u) { return __uint_as_float(u << 16); }
__device__ inline float bhi(unsigned u) { return __uint_as_float(u & 0xFFFF0000u); }
__device__ inline unsigned bpack(float lo, float hi) {
    return (unsigned)f2b(lo) | ((unsigned)f2b(hi) << 16);
}

// ---------------- weight folding ----------------
// A = Wl@Wn, B = (Wr+Ws)@Wn, c = (bl+bs)@Wn + bn   (per layer)
__global__ void prep_weights(
    const float* __restrict__ Wl1, const float* __restrict__ bl1,
    const float* __restrict__ Wr1, const float* __restrict__ Ws1,
    const float* __restrict__ bs1, const float* __restrict__ Wn1,
    const float* __restrict__ bn1,
    const float* __restrict__ Wlm, const float* __restrict__ blm,
    const float* __restrict__ Wrm, const float* __restrict__ Wsm,
    const float* __restrict__ bsm, const float* __restrict__ Wnm,
    const float* __restrict__ bnm,
    const float* __restrict__ Wl5, const float* __restrict__ bl5,
    const float* __restrict__ Wr5, const float* __restrict__ Ws5,
    const float* __restrict__ bs5, const float* __restrict__ Wn5,
    const float* __restrict__ bn5,
    float* __restrict__ wc1, float* __restrict__ c1,
    float* __restrict__ wcm, float* __restrict__ cm,
    float* __restrict__ wc5, float* __restrict__ c5)
{
    int layer = blockIdx.x;
    int t = threadIdx.x;
    if (layer == 0) {
        for (int idx = t; idx < FINN * Dh; idx += blockDim.x) {
            int k = idx / Dh, j = idx % Dh;
            float a = 0.f, b = 0.f;
            for (int d = 0; d < Dh; ++d) {
                float wn = Wn1[d * Dh + j];
                a += Wl1[k * Dh + d] * wn;
                b += (Wr1[k * Dh + d] + Ws1[k * Dh + d]) * wn;
            }
            wc1[k * 40 + j] = a;
            wc1[k * 40 + 20 + j] = b;
        }
        for (int j = t; j < Dh; j += blockDim.x) {
            float c0 = 0.f;
            for (int d = 0; d < Dh; ++d) c0 += (bl1[d] + bs1[d]) * Wn1[d * Dh + j];
            c1[j] = c0 + bn1[j];
        }
    } else if (layer <= 3) {
        int i = layer - 1;
        const float* Wl = Wlm + i * Dh * Dh;
        const float* Wr = Wrm + i * Dh * Dh;
        const float* Ws = Wsm + i * Dh * Dh;
        const float* Wn = Wnm + i * Dh * Dh;
        const float* bl = blm + i * Dh;
        const float* bs = bsm + i * Dh;
        const float* bn = bnm + i * Dh;
        float* wc = wcm + i * 800;
        float* cc = cm + i * 32;
        for (int idx = t; idx < Dh * Dh; idx += blockDim.x) {
            int k = idx / Dh, j = idx % Dh;
            float a = 0.f, b = 0.f;
            for (int d = 0; d < Dh; ++d) {
                float wn = Wn[d * Dh + j];
                a += Wl[k * Dh + d] * wn;
                b += (Wr[k * Dh + d] + Ws[k * Dh + d]) * wn;
            }
            wc[k * 40 + j] = a;
            wc[k * 40 + 20 + j] = b;
        }
        for (int j = t; j < Dh; j += blockDim.x) {
            float c0 = 0.f;
            for (int d = 0; d < Dh; ++d) c0 += (bl[d] + bs[d]) * Wn[d * Dh + j];
            cc[j] = c0 + bn[j];
        }
    } else {
        for (int idx = t; idx < Dh * Dout; idx += blockDim.x) {
            int k = idx / Dout, j = idx % Dout;
            float a = 0.f, b = 0.f;
            for (int d = 0; d < Dh; ++d) {
                float wn = Wn5[d * Dout + j];
                a += Wl5[k * Dh + d] * wn;
                b += (Wr5[k * Dh + d] + Ws5[k * Dh + d]) * wn;
            }
            wc5[k * 32 + j] = a;
            wc5[k * 32 + 16 + j] = b;
        }
        for (int j = t; j < Dout; j += blockDim.x) {
            float c0 = 0.f;
            for (int d = 0; d < Dh; ++d) c0 += (bl5[d] + bs5[d]) * Wn5[d * Dout + j];
            c5[j] = c0 + bn5[j];
        }
    }
}

// ---------------- CSR build: two-pass radix, no global atomics ----------------
__global__ __launch_bounds__(256) void hist1(const int* __restrict__ dst, unsigned* __restrict__ bhT) {
    __shared__ unsigned h[16 * NR];
    int b = blockIdx.x, t = threadIdx.x;
    for (int i = t; i < 16 * NR; i += 256) h[i] = 0;
    __syncthreads();
    int sub = t & 15;
    int e0 = b * P1E, e1 = min(e0 + P1E, Ne);
    for (int e = e0 + t; e < e1; e += 256) {
        int r = dst[e] / RSZ;
        atomicAdd(&h[sub * NR + r], 1u);
    }
    __syncthreads();
    if (t < NR) {
        unsigned s = 0;
        for (int i = 0; i < 16; ++i) s += h[i * NR + t];
        bhT[t * P1B + b] = s;   // transposed: [range][block]
    }
}

__global__ __launch_bounds__(1024) void scan1(
    const unsigned* __restrict__ bhT, unsigned* __restrict__ obhT, unsigned* __restrict__ rbase)
{
    __shared__ unsigned rtot[NR];
    int t = threadIdx.x;
    int w = t >> 6, lane = t & 63;
    constexpr int PER = (P1B + 63) / 64;  // 7
    if (w < NR) {
        unsigned v[PER];
        unsigned s = 0;
#pragma unroll
        for (int i = 0; i < PER; ++i) {
            int b = lane * PER + i;
            v[i] = (b < P1B) ? bhT[w * P1B + b] : 0u;
            s += v[i];
        }
        unsigned val = s;
        for (int off = 1; off < 64; off <<= 1) {
            unsigned u = __shfl_up(val, off, 64);
            if (lane >= off) val += u;
        }
        unsigned run = val - s;  // exclusive
#pragma unroll
        for (int i = 0; i < PER; ++i) {
            int b = lane * PER + i;
            if (b < P1B) obhT[w * P1B + b] = run;
            run += v[i];
        }
        if (lane == 63) rtot[w] = val;
    }
    __syncthreads();
    if (t == 0) {
        unsigned base = 0;
        for (int r = 0; r < NR; ++r) { rbase[r] = base; base += rtot[r]; }
        rbase[NR] = base;
    }
}

__global__ __launch_bounds__(256) void scatter1(
    const int* __restrict__ src, const int* __restrict__ dst,
    const unsigned* __restrict__ obhT, const unsigned* __restrict__ rbase,
    unsigned* __restrict__ ebuf)
{
    __shared__ unsigned cur[NR];
    int b = blockIdx.x, t = threadIdx.x;
    if (t < NR) cur[t] = rbase[t] + obhT[t * P1B + b];
    __syncthreads();
    int e0 = b * P1E, e1 = min(e0 + P1E, Ne);
    for (int e = e0 + t; e < e1; e += 256) {
        int d = dst[e];
        int r = d / RSZ;
        unsigned dl = (unsigned)(d - r * RSZ);
        unsigned pos = atomicAdd(&cur[r], 1u);
        ebuf[pos] = (dl << 17) | (unsigned)src[e];
    }
}

__global__ __launch_bounds__(256) void hist2(
    const unsigned* __restrict__ ebuf, const unsigned* __restrict__ rbase,
    unsigned short* __restrict__ part)
{
    __shared__ unsigned h[RSZ];   // 25 KB
    int b = blockIdx.x, t = threadIdx.x;
    int r = b % NR, s = b / NR;
    for (int i = t; i < RSZ; i += 256) h[i] = 0;
    __syncthreads();
    unsigned lo = rbase[r], hi = rbase[r + 1];
    unsigned step = (hi - lo + NSL - 1) / NSL;
    unsigned e0 = lo + (unsigned)s * step;
    unsigned e1 = e0 + step; if (e1 > hi) e1 = hi;
    for (unsigned e = e0 + t; e < e1; e += 256)
        atomicAdd(&h[ebuf[e] >> 17], 1u);
    __syncthreads();
    unsigned short* p = part + (size_t)b * RSZ;
    for (int i = t; i < RSZ; i += 256) p[i] = (unsigned short)h[i];
}

__global__ void col_prefix(unsigned short* __restrict__ part, unsigned* __restrict__ cnt) {
    int d = blockIdx.x * blockDim.x + threadIdx.x;
    if (d >= Nn) return;
    int r = d / RSZ, dl = d - r * RSZ;
    unsigned run = 0;
#pragma unroll
    for (int s = 0; s < NSL; ++s) {
        size_t idx = ((size_t)s * NR + r) * RSZ + dl;
        unsigned v = part[idx];
        part[idx] = (unsigned short)run;
        run += v;
    }
    cnt[d] = run;
}

__global__ void scan_blocksums(const unsigned* __restrict__ cnt, unsigned* __restrict__ bsum, int n) {
    __shared__ unsigned sd[256];
    int b = blockIdx.x, t = threadIdx.x;
    int base = b * 1024;
    unsigned s = 0;
    for (int i = t; i < 1024; i += 256) {
        int idx = base + i;
        if (idx < n) s += cnt[idx];
    }
    sd[t] = s;
    __syncthreads();
    for (int off = 128; off > 0; off >>= 1) {
        if (t < off) sd[t] += sd[t + off];
        __syncthreads();
    }
    if (t == 0) bsum[b] = sd[0];
}

__global__ void scan_bsum(unsigned* __restrict__ bsum, int nb) {
    __shared__ unsigned sh[128];
    int t = threadIdx.x;
    unsigned v = (t < nb) ? bsum[t] : 0u;
    sh[t] = v;
    __syncthreads();
    for (int off = 1; off < 128; off <<= 1) {
        unsigned add = (t >= off) ? sh[t - off] : 0u;
        __syncthreads();
        sh[t] += add;
        __syncthreads();
    }
    if (t < nb) bsum[t] = sh[t] - v;  // exclusive
}

__global__ void scan_final(const unsigned* __restrict__ cnt, const unsigned* __restrict__ bsum,
                           unsigned* __restrict__ offs, int n) {
    __shared__ unsigned wsum[4], woff[4];
    int b = blockIdx.x, t = threadIdx.x;
    int base = b * 1024 + t * 4;
    unsigned v[4];
    unsigned s = 0;
#pragma unroll
    for (int i = 0; i < 4; ++i) {
        int idx = base + i;
        v[i] = (idx < n) ? cnt[idx] : 0u;
        s += v[i];
    }
    unsigned lane = t & 63;
    int w = t >> 6;
    unsigned val = s;
    for (int off = 1; off < 64; off <<= 1) {
        unsigned u = __shfl_up(val, off, 64);
        if (lane >= off) val += u;
    }
    if (lane == 63) wsum[w] = val;
    __syncthreads();
    if (t == 0) {
        unsigned r = 0;
        for (int i = 0; i < 4; ++i) { woff[i] = r; r += wsum[i]; }
    }
    __syncthreads();
    unsigned run = bsum[b] + woff[w] + (val - s);
#pragma unroll
    for (int i = 0; i < 4; ++i) {
        int idx = base + i;
        if (idx < n) {
            offs[idx] = run;
            run += v[i];
            if (idx == n - 1) offs[n] = run;
        }
    }
}

__global__ __launch_bounds__(256) void fill2(
    const unsigned* __restrict__ ebuf, const unsigned* __restrict__ rbase,
    const unsigned* __restrict__ offs, const unsigned short* __restrict__ part,
    unsigned* __restrict__ csr)
{
    __shared__ unsigned cur[RSZ];   // 25 KB
    int b = blockIdx.x, t = threadIdx.x;
    int r = b % NR, s = b / NR;
    int lon = r * RSZ;
    const unsigned short* p = part + (size_t)b * RSZ;
    for (int i = t; i < RSZ; i += 256)
        cur[i] = offs[lon + i] + p[i];
    __syncthreads();
    unsigned lo = rbase[r], hi = rbase[r + 1];
    unsigned step = (hi - lo + NSL - 1) / NSL;
    unsigned e0 = lo + (unsigned)s * step;
    unsigned e1 = e0 + step; if (e1 > hi) e1 = hi;
    for (unsigned e = e0 + t; e < e1; e += 256) {
        unsigned v = ebuf[e];
        unsigned pos = atomicAdd(&cur[v >> 17], 1u);
        csr[pos] = v & 0x1FFFFu;
    }
}

// ---------------- fused (lazy-BN+ReLU) + projection, lane-split ----------------
// CL = 2*(XS/8) lanes per node; each lane computes 8 of the 2*FO outputs and
// writes one 16B chunk of xa or xb. Weights staged in LDS. Grid = Nn*CL threads.
template <int FINt, int FO, bool NORM, bool INBF16>
__global__ __launch_bounds__(256) void gemm_kernel(
    const void* __restrict__ xin_, const float* __restrict__ stats,
    const float* __restrict__ g, const float* __restrict__ be,
    const float* __restrict__ wc, const float* __restrict__ cvec,
    unsigned short* __restrict__ xa, unsigned short* __restrict__ xb)
{
    constexpr int XS  = ((FO + 7) / 8) * 8;    // output row stride (u16)
    constexpr int XSI = ((FINt + 7) / 8) * 8;  // input row stride when bf16
    constexpr int CH  = XS / 8;                // 16B chunks per half
    constexpr int CL  = 2 * CH;                // lanes per node
    __shared__ float swl[FINt * 2 * FO + 8];   // +8: OOB-j reads stay in-bounds
    __shared__ float sscale[Dh], sshift[Dh];
    int t = threadIdx.x;
    for (int i = t; i < FINt * 2 * FO; i += 256) swl[i] = wc[i];
    if (t < 8) swl[FINt * 2 * FO + t] = 0.f;
    if (NORM) {
        if (t < Dh) {
            float mu = stats[t] * (1.0f / Nn);
            float var = stats[32 + t] * (1.0f / Nn) - mu * mu;
            float sc = g[t] * rsqrtf(var + EPSV);
            sscale[t] = sc;
            sshift[t] = be[t] - mu * sc;
        }
    }
    __syncthreads();
    int tid = blockIdx.x * 256 + t;
    int n = tid / CL;
    int c = tid % CL;
    if (n >= Nn) return;
    int half = c / CH, cc = c % CH;
    int off = half * FO + cc * 8;
    int jmax = (cc == CH - 1) ? (FO - (CH - 1) * 8) : 8;

    float acc[8];
#pragma unroll
    for (int j = 0; j < 8; ++j) acc[j] = 0.f;

#pragma unroll
    for (int k4 = 0; k4 < FINt / 4; ++k4) {
        float xs[4];
        if (INBF16) {
            const unsigned short* xr = (const unsigned short*)xin_ + (size_t)n * XSI;
            ushort4 v = *(const ushort4*)(xr + 4 * k4);
            xs[0] = b2f(v.x); xs[1] = b2f(v.y); xs[2] = b2f(v.z); xs[3] = b2f(v.w);
        } else {
            const float* xr = (const float*)xin_ + (size_t)n * FINt;
            float4 v = *(const float4*)(xr + 4 * k4);
            xs[0] = v.x; xs[1] = v.y; xs[2] = v.z; xs[3] = v.w;
        }
        if (NORM) {
#pragma unroll
            for (int kk = 0; kk < 4; ++kk)
                xs[kk] = fmaxf(xs[kk] * sscale[4 * k4 + kk] + sshift[4 * k4 + kk], 0.0f);
        }
#pragma unroll
        for (int kk = 0; kk < 4; ++kk) {
            float xk = xs[kk];
            const float* wr = &swl[(4 * k4 + kk) * (2 * FO) + off];
#pragma unroll
            for (int j = 0; j < 8; ++j) acc[j] = fmaf(xk, wr[j], acc[j]);
        }
    }

    float hv[8];
#pragma unroll
    for (int j = 0; j < 8; ++j) hv[j] = acc[j];
    if (half) {
#pragma unroll
        for (int j = 0; j < 8; ++j) hv[j] += cvec[cc * 8 + j];   // cvec padded to 32
    }
#pragma unroll
    for (int j = 0; j < 8; ++j) if (j >= jmax) hv[j] = 0.f;

    unsigned short* dstp = (half ? xb : xa) + (size_t)n * XS + cc * 8;
    uint4 w;
    w.x = bpack(hv[0], hv[1]); w.y = bpack(hv[2], hv[3]);
    w.z = bpack(hv[4], hv[5]); w.w = bpack(hv[6], hv[7]);
    *(uint4*)dstp = w;
}

// ---------------- pull aggregation + combine (+ BN stats) ----------------
// C = ceil(F/8) lanes per node; one 16B gather per edge per lane.
// Gather loop: fully masked 16-deep batches — no serial remainder; duplicate
// (masked) gathers use csr[b] (same-address broadcast, free).
template <int F, bool WITH_STATS, bool OUTBF16>
__global__ __launch_bounds__(256) void pull_kernel(
    const unsigned* __restrict__ offs, const unsigned* __restrict__ csr,
    const unsigned short* __restrict__ xa, const unsigned short* __restrict__ xb,
    void* __restrict__ out_, float* __restrict__ stats)
{
    constexpr int C  = (F + 7) / 8;
    constexpr int XS = C * 8;
    __shared__ float sstat[2 * F];
    int t = threadIdx.x;
    if (WITH_STATS) {
        if (t < 2 * F) sstat[t] = 0.f;
        __syncthreads();
    }
    int tid = blockIdx.x * blockDim.x + t;
    int n = tid / C;
    int c = tid % C;
    int valid = (c == C - 1) ? (F - 8 * (C - 1)) : 8;
    bool act = (n < Nn);
    float h[8];
    if (act) {
        unsigned b = offs[n], e = offs[n + 1];
        const unsigned short* base = xa + c * 8;
        float acc[8];
#pragma unroll
        for (int j = 0; j < 8; ++j) acc[j] = 0.f;
        for (unsigned k = b; k < e; k += 16) {
            unsigned s[16];
            float m[16];
#pragma unroll
            for (int i = 0; i < 16; ++i) {
                unsigned kk = k + i;
                bool in = kk < e;
                s[i] = csr[in ? kk : b];
                m[i] = in ? 1.0f : 0.0f;
            }
            uint4 v[16];
#pragma unroll
            for (int i = 0; i < 16; ++i) v[i] = *(const uint4*)(base + (size_t)s[i] * XS);
#pragma unroll
            for (int i = 0; i < 16; ++i) {
                acc[0] = fmaf(m[i], blo(v[i].x), acc[0]);
                acc[1] = fmaf(m[i], bhi(v[i].x), acc[1]);
                acc[2] = fmaf(m[i], blo(v[i].y), acc[2]);
                acc[3] = fmaf(m[i], bhi(v[i].y), acc[3]);
                acc[4] = fmaf(m[i], blo(v[i].z), acc[4]);
                acc[5] = fmaf(m[i], bhi(v[i].z), acc[5]);
                acc[6] = fmaf(m[i], blo(v[i].w), acc[6]);
                acc[7] = fmaf(m[i], bhi(v[i].w), acc[7]);
            }
        }
        float inv = 1.0f / fmaxf((float)(e - b), 1.0f);
        uint4 xv = *(const uint4*)(xb + (size_t)n * XS + c * 8);
        float xf[8] = { blo(xv.x), bhi(xv.x), blo(xv.y), bhi(xv.y),
                        blo(xv.z), bhi(xv.z), blo(xv.w), bhi(xv.w) };
#pragma unroll
        for (int j = 0; j < 8; ++j) h[j] = fmaf(acc[j], inv, xf[j]);
        if (OUTBF16) {
            unsigned short* o = (unsigned short*)out_ + (size_t)n * XS + c * 8;
            if (valid == 8) {
                uint4 w;
                w.x = bpack(h[0], h[1]); w.y = bpack(h[2], h[3]);
                w.z = bpack(h[4], h[5]); w.w = bpack(h[6], h[7]);
                *(uint4*)o = w;
            } else {
                ushort4 w4;
                w4.x = f2b(h[0]); w4.y = f2b(h[1]); w4.z = f2b(h[2]); w4.w = f2b(h[3]);
                *(ushort4*)o = w4;
            }
        } else {
            float* o = (float*)out_ + (size_t)n * F + c * 8;   // final out unpadded
            float4 v0; v0.x = h[0]; v0.y = h[1]; v0.z = h[2]; v0.w = h[3];
            *(float4*)o = v0;
            if (valid == 8) {
                float4 v1; v1.x = h[4]; v1.y = h[5]; v1.z = h[6]; v1.w = h[7];
                *(float4*)(o + 4) = v1;
            }
        }
    }
    if (WITH_STATS) {
        if (act) {
            for (int j = 0; j < valid; ++j) {
                atomicAdd(&sstat[c * 8 + j], h[j]);
                atomicAdd(&sstat[F + c * 8 + j], h[j] * h[j]);
            }
        }
        __syncthreads();
        if (t < F) {
            atomicAdd(&stats[t], sstat[t]);
        } else if (t < 2 * F) {
            atomicAdd(&stats[32 + (t - F)], sstat[t]);
        }
    }
}

// ---------------- launch ----------------
extern "C" void kernel_launch(void* const* d_in, const int* in_sizes, int n_in,
                              void* d_out, int out_size, void* d_ws, size_t ws_size,
                              hipStream_t stream) {
    const float* x   = (const float*)d_in[0];
    const int* ei    = (const int*)d_in[1];
    const int* esrc  = ei;
    const int* edst  = ei + Ne;
    const float* Wl1 = (const float*)d_in[3];
    const float* bl1 = (const float*)d_in[4];
    const float* Wr1 = (const float*)d_in[5];
    const float* Ws1 = (const float*)d_in[6];
    const float* bs1 = (const float*)d_in[7];
    const float* Wn1 = (const float*)d_in[8];
    const float* bn1 = (const float*)d_in[9];
    const float* g1  = (const float*)d_in[10];
    const float* be1 = (const float*)d_in[11];
    const float* Wlm = (const float*)d_in[12];
    const float* blm = (const float*)d_in[13];
    const float* Wrm = (const float*)d_in[14];
    const float* Wsm = (const float*)d_in[15];
    const float* bsm = (const float*)d_in[16];
    const float* Wnm = (const float*)d_in[17];
    const float* bnm = (const float*)d_in[18];
    const float* gm  = (const float*)d_in[19];
    const float* bem = (const float*)d_in[20];
    const float* Wl5 = (const float*)d_in[21];
    const float* bl5 = (const float*)d_in[22];
    const float* Wr5 = (const float*)d_in[23];
    const float* Ws5 = (const float*)d_in[24];
    const float* bs5 = (const float*)d_in[25];
    const float* Wn5 = (const float*)d_in[26];
    const float* bn5 = (const float*)d_in[27];

    float* ws   = (float*)d_ws;
    unsigned* u = (unsigned*)d_ws;
    float* wc1   = ws + OFF_WC1;
    float* c1    = ws + OFF_C1;
    float* wcm   = ws + OFF_WCM;
    float* cm    = ws + OFF_CM;
    float* wc5   = ws + OFF_WC5;
    float* c5    = ws + OFF_C5;
    float* stats = ws + OFF_ST;
    unsigned* offs = u + OFF_OFFS;
    unsigned* bsum = u + OFF_BSUM;
    unsigned* cnt  = u + OFF_CNT;
    unsigned* csr  = u + OFF_CSR;
    unsigned short* xa = (unsigned short*)(ws + OFF_XA);
    unsigned* ebuf = u + OFF_XA;                           // aliases xa region (dead before gemm1)
    unsigned short* xb = (unsigned short*)(ws + OFF_XB);
    unsigned short* part = (unsigned short*)(ws + OFF_XB); // aliases xb region (dead before gemm1)
    unsigned short* hp = (unsigned short*)(ws + OFF_HP);
    unsigned* bhT  = u + OFF_BHT;                          // alias hp head (CSR-build phase only)
    unsigned* obhT = u + OFF_OBHT;
    unsigned* rbase = u + OFF_RB;

    hipMemsetAsync(stats, 0, 256 * sizeof(float), stream);

    prep_weights<<<5, 256, 0, stream>>>(Wl1, bl1, Wr1, Ws1, bs1, Wn1, bn1,
                                        Wlm, blm, Wrm, Wsm, bsm, Wnm, bnm,
                                        Wl5, bl5, Wr5, Ws5, bs5, Wn5, bn5,
                                        wc1, c1, wcm, cm, wc5, c5);

    // ---- CSR build (two-pass radix, no global atomics) ----
    hist1<<<P1B, 256, 0, stream>>>(edst, bhT);
    scan1<<<1, 1024, 0, stream>>>(bhT, obhT, rbase);
    scatter1<<<P1B, 256, 0, stream>>>(esrc, edst, obhT, rbase, ebuf);
    hist2<<<NR * NSL, 256, 0, stream>>>(ebuf, rbase, part);
    col_prefix<<<(Nn + 255) / 256, 256, 0, stream>>>(part, cnt);
    constexpr int NB = (Nn + 1023) / 1024;  // 98
    scan_blocksums<<<NB, 256, 0, stream>>>(cnt, bsum, Nn);
    scan_bsum<<<1, 128, 0, stream>>>(bsum, NB);
    scan_final<<<NB, 256, 0, stream>>>(cnt, bsum, offs, Nn);
    fill2<<<NR * NSL, 256, 0, stream>>>(ebuf, rbase, offs, part, csr);

    int gblk20 = (Nn * 6 + 255) / 256;        // 2344 (gemm FO=20: 6 lanes/node)
    int gblk16 = (Nn * 4 + 255) / 256;        // 1563 (gemm FO=16: 4 lanes/node)
    int pblk20 = (Nn * 3 + 255) / 256;        // 1172 (pull F=20: 3 lanes/node)
    int pblk16 = (Nn * 2 + 255) / 256;        // 782  (pull F=16: 2 lanes/node)

    // layer 1
    gemm_kernel<FINN, Dh, false, false><<<gblk20, 256, 0, stream>>>(x, nullptr, nullptr, nullptr, wc1, c1, xa, xb);
    pull_kernel<Dh, true, true><<<pblk20, 256, 0, stream>>>(offs, csr, xa, xb, hp, stats + 0);
    // layer 2
    gemm_kernel<Dh, Dh, true, true><<<gblk20, 256, 0, stream>>>(hp, stats + 0, g1, be1, wcm + 0, cm + 0, xa, xb);
    pull_kernel<Dh, true, true><<<pblk20, 256, 0, stream>>>(offs, csr, xa, xb, hp, stats + 64);
    // layer 3
    gemm_kernel<Dh, Dh, true, true><<<gblk20, 256, 0, stream>>>(hp, stats + 64, gm + 0, bem + 0, wcm + 800, cm + 32, xa, xb);
    pull_kernel<Dh, true, true><<<pblk20, 256, 0, stream>>>(offs, csr, xa, xb, hp, stats + 128);
    // layer 4
    gemm_kernel<Dh, Dh, true, true><<<gblk20, 256, 0, stream>>>(hp, stats + 128, gm + 20, bem + 20, wcm + 1600, cm + 64, xa, xb);
    pull_kernel<Dh, true, true><<<pblk20, 256, 0, stream>>>(offs, csr, xa, xb, hp, stats + 192);
    // layer 5 (no BN/ReLU at output; lazy-norm of layer-4 applied in gemm)
    gemm_kernel<Dh, Dout, true, true><<<gblk16, 256, 0, stream>>>(hp, stats + 192, gm + 40, bem + 40, wc5, c5, xa, xb);
    pull_kernel<Dout, false, false><<<pblk16, 256, 0, stream>>>(offs, csr, xa, xb, d_out, nullptr);
}